// Round 10
// baseline (119.597 us; speedup 1.0000x reference)
//
#include <hip/hip_runtime.h>
#include <hip/hip_bf16.h>
#include <stdint.h>

// MultiheadAttention: B=2 L=2048 DIM=1024 H=16 d=64, scale = DIM^-0.5 = 1/32
// convert(f32->bf16) -> QKV gemm (bf16 mfma) -> flash attn (32x32 mfma,
// fixed-max in-register softmax, KV-SPLIT: 4 waves = 2 rowgroups x 2 KV
// halves, 16 waves/CU) -> O gemm.
// ws layout (ushort elems): xb[4M] wqb[1M] wkb[1M] wvb[1M] wob[1M]
//                           qb[4M] kb[4M] vtb[4M] ab[4M]  = 48MB

typedef __attribute__((ext_vector_type(8))) short short8;
typedef __attribute__((ext_vector_type(4))) float f32x4;
typedef __attribute__((ext_vector_type(16))) float f32x16;

#define MFMA(a, b, c) __builtin_amdgcn_mfma_f32_16x16x32_bf16((a), (b), (c), 0, 0, 0)
#define MFMA32(a, b, c) __builtin_amdgcn_mfma_f32_32x32x16_bf16((a), (b), (c), 0, 0, 0)

#if __has_builtin(__builtin_amdgcn_exp2f)
#define EXP2(x) __builtin_amdgcn_exp2f(x)
#else
#define EXP2(x) exp2f(x)
#endif

__device__ __forceinline__ ushort f2bf(float f) {
  uint32_t u = __builtin_bit_cast(uint32_t, f);
  u += 0x7fffu + ((u >> 16) & 1u);
  return (ushort)(u >> 16);
}

// packed f32x2 -> bf16x2 (library path, for GEMM epilogues)
__device__ __forceinline__ uint32_t pkbf(float lo, float hi) {
  __hip_bfloat162 h = __float22bfloat162_rn(make_float2(lo, hi));
  uint32_t u;
  __builtin_memcpy(&u, &h, 4);
  return u;
}

// single-instruction packed cvt (RNE): dst = {bf16(lo), bf16(hi)}
__device__ __forceinline__ uint32_t cvtpk(float lo, float hi) {
  uint32_t u;
  asm("v_cvt_pk_bf16_f32 %0, %1, %2" : "=v"(u) : "v"(lo), "v"(hi));
  return u;
}

// v_permlane32_swap_b32: a' = [a_lo | b_lo], b' = [a_hi | b_hi]
__device__ __forceinline__ void pl32swap(uint32_t& a, uint32_t& b) {
  asm("v_permlane32_swap_b32 %0, %1" : "+v"(a), "+v"(b));
}

__device__ __forceinline__ void gl_lds16(const void* g, void* l) {
  __builtin_amdgcn_global_load_lds(
      (const __attribute__((address_space(1))) unsigned int*)g,
      (__attribute__((address_space(3))) unsigned int*)l, 16, 0, 0);
}

// ---------------- kernel 0: f32 -> bf16 conversion ----------------
__global__ __launch_bounds__(256) void convert_all(
    const float* __restrict__ x, const float* __restrict__ wq,
    const float* __restrict__ wk, const float* __restrict__ wv,
    const float* __restrict__ wo, ushort* __restrict__ dst) {
  size_t i4 = (size_t)blockIdx.x * 256 + threadIdx.x;  // 2M float4's
  size_t e = i4 * 4;
  const float* src; size_t off;
  if (e < 4194304u)      { src = x;  off = e; }
  else if (e < 5242880u) { src = wq; off = e - 4194304u; }
  else if (e < 6291456u) { src = wk; off = e - 5242880u; }
  else if (e < 7340032u) { src = wv; off = e - 6291456u; }
  else                   { src = wo; off = e - 7340032u; }
  float4 v = *(const float4*)(src + off);
  ushort4 o = { f2bf(v.x), f2bf(v.y), f2bf(v.z), f2bf(v.w) };
  *(ushort4*)(dst + e) = o;
}

// ---------------- kernel 1: QKV projections ----------------
// y[m][n] = sum_k A[m][k] * W[n][k] + bias[n]   (torch Linear, B^T form)
// z=0: Q *= (1/32)*log2(e), store [bh][l][64]
// z=1: K store [bh][l][64]
// z=2: V store transposed [bh][64][l]
__global__ __launch_bounds__(256) void gemm_qkv(
    const ushort* __restrict__ xb,
    const ushort* __restrict__ wqb, const ushort* __restrict__ wkb,
    const ushort* __restrict__ wvb,
    const float* __restrict__ bq_, const float* __restrict__ bk_,
    const float* __restrict__ bv_,
    ushort* __restrict__ qout, ushort* __restrict__ kout,
    ushort* __restrict__ vtout) {
  __shared__ __align__(16) ushort As[128 * 32];
  __shared__ __align__(16) ushort Bs[128 * 32];
  const int z = blockIdx.z;
  const int bn = blockIdx.x, bm = blockIdx.y;
  const int t = threadIdx.x;
  const int w = t >> 6, lane = t & 63;
  const int wr = w >> 1, wc = w & 1;
  const int l15 = lane & 15, l4 = lane >> 4;

  const ushort* wb = (z == 0) ? wqb : (z == 1 ? wkb : wvb);
  const float* bias = (z == 0) ? bq_ : (z == 1 ? bk_ : bv_);

  f32x4 acc[4][4] = {};

  for (int kt = 0; kt < 32; ++kt) {
    __syncthreads();
#pragma unroll
    for (int rr = 0; rr < 2; ++rr) {
      int c = t + rr * 256;
      int row = c >> 2, cin = c & 3;
      gl_lds16(xb + (bm * 128 + row) * 1024 + kt * 32 + cin * 8, (void*)&As[c * 8]);
      gl_lds16(wb + (bn * 128 + row) * 1024 + kt * 32 + cin * 8, (void*)&Bs[c * 8]);
    }
    __syncthreads();
    short8 af[4], bfr[4];
#pragma unroll
    for (int mf = 0; mf < 4; ++mf)
      af[mf] = *(const short8*)&As[(wr * 64 + mf * 16 + l15) * 32 + l4 * 8];
#pragma unroll
    for (int nf = 0; nf < 4; ++nf)
      bfr[nf] = *(const short8*)&Bs[(wc * 64 + nf * 16 + l15) * 32 + l4 * 8];
    __builtin_amdgcn_s_setprio(1);
#pragma unroll
    for (int mf = 0; mf < 4; ++mf)
#pragma unroll
      for (int nf = 0; nf < 4; ++nf)
        acc[mf][nf] = MFMA(af[mf], bfr[nf], acc[mf][nf]);
    __builtin_amdgcn_s_setprio(0);
  }

  const float qsc = 0.045084439f;  // (1/32) * log2(e)
#pragma unroll
  for (int mf = 0; mf < 4; ++mf) {
#pragma unroll
    for (int nf = 0; nf < 4; ++nf) {
      int n = bn * 128 + wc * 64 + nf * 16 + l15;
      int m0 = bm * 128 + wr * 64 + mf * 16 + l4 * 4;
      float b = bias[n];
      float vals[4];
#pragma unroll
      for (int r = 0; r < 4; ++r) vals[r] = acc[mf][nf][r] + b;
      int bb = m0 >> 11, l0 = m0 & 2047;
      int h = n >> 6, d = n & 63;
      int bh = bb * 16 + h;
      if (z == 2) {
        *(uint2*)&vtout[(bh * 64 + d) * 2048 + l0] =
            make_uint2(pkbf(vals[0], vals[1]), pkbf(vals[2], vals[3]));
      } else if (z == 0) {
#pragma unroll
        for (int r = 0; r < 4; ++r)
          qout[(bh * 2048 + l0 + r) * 64 + d] = f2bf(vals[r] * qsc);
      } else {
#pragma unroll
        for (int r = 0; r < 4; ++r)
          kout[(bh * 2048 + l0 + r) * 64 + d] = f2bf(vals[r]);
      }
    }
  }
}

// ---------------- kernel 2: flash attention (KV-split, 16 waves/CU) --------
// Block: 256 thr = 4 waves = {rowgrp 0,1} x {KV-half 0,1}; 64 q-rows/block.
// Grid 1024 = 4 blocks/CU -> 16 waves/CU (4/SIMD) — 2x occupancy vs 512-grid.
// Fixed-max softmax is additive across KV tiles, so each wave processes 32
// q-rows over HALF the KV range (1024 j); halves combine via LDS at the end.
// Per iter one [64][64] K tile and V^T tile hold BOTH halves' 32-j subtiles
// side by side (rows stay 128B); 2-buffer dbuf, 32 KB LDS total.
// Swapped QK^T via mfma_32x32x16; P repack via v_cvt_pk_bf16_f32 +
// v_permlane32_swap; per-lane partial sums, combined in the epilogue.
__global__ __launch_bounds__(256, 4) void attn(
    const ushort* __restrict__ qb, const ushort* __restrict__ kb,
    const ushort* __restrict__ vtb, ushort* __restrict__ aout) {
  __shared__ __align__(16) ushort Ks[2][64 * 64];
  __shared__ __align__(16) ushort Vs[2][64 * 64];
  const int bid = blockIdx.x;
  const int xcd = bid & 7, idx = bid >> 3;
  const int bh = xcd * 4 + (idx >> 5);
  const int it = idx & 31;
  const int t = threadIdx.x, w = t >> 6, lane = t & 63;
  const int l31 = lane & 31, hi = lane >> 5;
  const int rg = w & 1;          // row group (which 32 q-rows)
  const int half = w >> 1;       // KV half (j < 1024 vs j >= 1024)
  const size_t kvbase = (size_t)bh * (2048 * 64);
  const int i0 = it * 64 + rg * 32;

  // staging: per buffer-fill, K = 512 chunks of 16B, V = 512 chunks.
  // K tile rows r<32 = half0 j's (jt*32+r), r>=32 = half1 (1024+jt*32+r-32).
  // V tile [64 d][64 j]: within-row chunk o<4 = half0 j's, o>=4 = half1.
#define STAGE(bufi, jts)                                                     \
  {                                                                          \
    const int jb0 = (jts) * 32, jb1 = 1024 + (jts) * 32;                     \
    _Pragma("unroll")                                                        \
    for (int rr = 0; rr < 2; ++rr) {                                         \
      int c = t + rr * 256;                                                  \
      int r = c >> 3, o = (c & 7) ^ (r & 7);                                 \
      int jr = (r < 32) ? (jb0 + r) : (jb1 + r - 32);                        \
      gl_lds16(kb + kvbase + (size_t)jr * 64 + o * 8,                        \
               (void*)&Ks[bufi][c * 8]);                                     \
      int jc = (o < 4) ? (jb0 + o * 8) : (jb1 + (o - 4) * 8);                \
      gl_lds16(vtb + kvbase + (size_t)r * 2048 + jc,                         \
               (void*)&Vs[bufi][c * 8]);                                     \
    }                                                                        \
  }

  // Q as B-operand: lane holds Q[i0+l31][k = ks*16 + hi*8 + e]
  short8 qf[4];
#pragma unroll
  for (int ks = 0; ks < 4; ++ks)
    qf[ks] = *(const short8*)&qb[kvbase + (size_t)(i0 + l31) * 64 + ks * 16 + hi * 8];

  f32x16 ot0 = {}, ot1 = {};
  float ts0 = 0.f, ts1 = 0.f, ts2 = 0.f, ts3 = 0.f;
  const int swz = l31 & 7;
  const int rowk = half * 32 + l31;  // this wave's K rows in the packed tile

  STAGE(0, 0);
  __syncthreads();

  for (int jt = 0; jt < 32; ++jt) {
    const int cur = jt & 1;
    if (jt < 31) STAGE(cur ^ 1, jt + 1);

    const ushort* Kc = &Ks[cur][0];
    const ushort* Vc = &Vs[cur][0];

    // K A-frags (row j = rowk, k = ks*16+hi*8), V^T A-frags (row d =
    // mf*32+l31, k chunk = half*4 + s*2 + hi), both XOR-swizzled.
    short8 ka[4], va0[2], va1[2];
#pragma unroll
    for (int ks = 0; ks < 4; ++ks) {
      int ck = (ks * 2 + hi) ^ swz;
      ka[ks] = *(const short8*)&Kc[rowk * 64 + ck * 8];
    }
#pragma unroll
    for (int s = 0; s < 2; ++s) {
      int cv = (half * 4 + s * 2 + hi) ^ swz;
      va0[s] = *(const short8*)&Vc[l31 * 64 + cv * 8];
      va1[s] = *(const short8*)&Vc[(32 + l31) * 64 + cv * 8];
    }

    // S^T = K . Q^T  (one 32x32 j-block per wave, k=d in 4 steps)
    f32x16 st = {};
    __builtin_amdgcn_s_setprio(1);
#pragma unroll
    for (int ks = 0; ks < 4; ++ks) st = MFMA32(ka[ks], qf[ks], st);
    __builtin_amdgcn_s_setprio(0);

    // P = exp2(S) (fixed max = 0), 4 independent partial sums
    f32x16 p;
#pragma unroll
    for (int r = 0; r < 16; r += 4) {
      p[r] = EXP2(st[r]);         ts0 += p[r];
      p[r + 1] = EXP2(st[r + 1]); ts1 += p[r + 1];
      p[r + 2] = EXP2(st[r + 2]); ts2 += p[r + 2];
      p[r + 3] = EXP2(st[r + 3]); ts3 += p[r + 3];
    }

    // repack P -> PV B-operand (two k-steps of 16 j's)
    short8 pb[2];
#pragma unroll
    for (int s = 0; s < 2; ++s) {
      const int R = 8 * s;
      uint32_t c01 = cvtpk(p[R + 0], p[R + 1]);
      uint32_t c23 = cvtpk(p[R + 2], p[R + 3]);
      uint32_t c45 = cvtpk(p[R + 4], p[R + 5]);
      uint32_t c67 = cvtpk(p[R + 6], p[R + 7]);
      pl32swap(c01, c45);
      pl32swap(c23, c67);
      union { uint32_t u[4]; short8 s8; } pk;
      pk.u[0] = c01; pk.u[1] = c23; pk.u[2] = c45; pk.u[3] = c67;
      pb[s] = pk.s8;
    }

    // O^T += V^T . P^T  (m = d in two 32-blocks, k = 32 j's in 2 steps)
    __builtin_amdgcn_s_setprio(1);
#pragma unroll
    for (int s = 0; s < 2; ++s) {
      ot0 = MFMA32(va0[s], pb[s], ot0);
      ot1 = MFMA32(va1[s], pb[s], ot1);
    }
    __builtin_amdgcn_s_setprio(0);

    __syncthreads();
  }

  // ---- combine the two KV halves (additive O and lsum) via LDS ----
  float lsum = (ts0 + ts1) + (ts2 + ts3);
  float* sh = (float*)&Ks[0][0];  // 32KB scratch, safe after final barrier
  float* base = sh + rg * 2560;   // per-rowgroup region: 64 lanes x 40 f32
  if (half == 1) {
#pragma unroll
    for (int g = 0; g < 4; ++g) {
      f32x4 q0 = { ot0[g * 4], ot0[g * 4 + 1], ot0[g * 4 + 2], ot0[g * 4 + 3] };
      f32x4 q1 = { ot1[g * 4], ot1[g * 4 + 1], ot1[g * 4 + 2], ot1[g * 4 + 3] };
      *(f32x4*)&base[lane * 40 + g * 4] = q0;
      *(f32x4*)&base[lane * 40 + 16 + g * 4] = q1;
    }
    base[lane * 40 + 32] = lsum;
  }
  __syncthreads();
  if (half == 0) {
#pragma unroll
    for (int g = 0; g < 4; ++g) {
      f32x4 q0 = *(const f32x4*)&base[lane * 40 + g * 4];
      f32x4 q1 = *(const f32x4*)&base[lane * 40 + 16 + g * 4];
#pragma unroll
      for (int e = 0; e < 4; ++e) {
        ot0[g * 4 + e] += q0[e];
        ot1[g * 4 + e] += q1[e];
      }
    }
    lsum += base[lane * 40 + 32];
    // cross-half (hi) combine of lsum
    uint32_t a = __builtin_bit_cast(uint32_t, lsum);
    uint32_t b = a;
    pl32swap(a, b);
    lsum = __builtin_bit_cast(float, a) + __builtin_bit_cast(float, b);

    const int bb = bh >> 4, h = bh & 15;
    float inv = 1.0f / lsum;
    ushort* orow = aout + (size_t)(bb * 2048 + i0 + l31) * 1024 + h * 64;
#pragma unroll
    for (int mf = 0; mf < 2; ++mf) {
      f32x16 o = mf ? ot1 : ot0;
#pragma unroll
      for (int g = 0; g < 4; ++g) {
        int d0 = mf * 32 + g * 8 + hi * 4;
        *(uint2*)(orow + d0) = make_uint2(
            cvtpk(o[g * 4 + 0] * inv, o[g * 4 + 1] * inv),
            cvtpk(o[g * 4 + 2] * inv, o[g * 4 + 3] * inv));
      }
    }
  }
#undef STAGE
}

// ---------------- kernel 3: output projection (f32 out + bias) ----------------
__global__ __launch_bounds__(256) void gemm_out(
    const ushort* __restrict__ ab, const ushort* __restrict__ wob,
    const float* __restrict__ bo_, float* __restrict__ out) {
  __shared__ __align__(16) ushort As[128 * 32];
  __shared__ __align__(16) ushort Bs[128 * 32];
  const int bn = blockIdx.x, bm = blockIdx.y;
  const int t = threadIdx.x;
  const int w = t >> 6, lane = t & 63;
  const int wr = w >> 1, wc = w & 1;
  const int l15 = lane & 15, l4 = lane >> 4;

  f32x4 acc[4][4] = {};

  for (int kt = 0; kt < 32; ++kt) {
    __syncthreads();
#pragma unroll
    for (int rr = 0; rr < 2; ++rr) {
      int c = t + rr * 256;
      int row = c >> 2, cin = c & 3;
      gl_lds16(ab + (bm * 128 + row) * 1024 + kt * 32 + cin * 8, (void*)&As[c * 8]);
      gl_lds16(wob + (bn * 128 + row) * 1024 + kt * 32 + cin * 8, (void*)&Bs[c * 8]);
    }
    __syncthreads();
    short8 af[4], bfr[4];
#pragma unroll
    for (int mf = 0; mf < 4; ++mf)
      af[mf] = *(const short8*)&As[(wr * 64 + mf * 16 + l15) * 32 + l4 * 8];
#pragma unroll
    for (int nf = 0; nf < 4; ++nf)
      bfr[nf] = *(const short8*)&Bs[(wc * 64 + nf * 16 + l15) * 32 + l4 * 8];
    __builtin_amdgcn_s_setprio(1);
#pragma unroll
    for (int mf = 0; mf < 4; ++mf)
#pragma unroll
      for (int nf = 0; nf < 4; ++nf)
        acc[mf][nf] = MFMA(af[mf], bfr[nf], acc[mf][nf]);
    __builtin_amdgcn_s_setprio(0);
  }

#pragma unroll
  for (int mf = 0; mf < 4; ++mf)
#pragma unroll
    for (int nf = 0; nf < 4; ++nf) {
      int n = bn * 128 + wc * 64 + nf * 16 + l15;
      int m0 = bm * 128 + wr * 64 + mf * 16 + l4 * 4;
      float b = bo_[n];
#pragma unroll
      for (int r = 0; r < 4; ++r)
        out[(size_t)(m0 + r) * 1024 + n] = acc[mf][nf][r] + b;
    }
}

extern "C" void kernel_launch(void* const* d_in, const int* in_sizes, int n_in,
                              void* d_out, int out_size, void* d_ws, size_t ws_size,
                              hipStream_t stream) {
  const float* x  = (const float*)d_in[0];
  const float* wq = (const float*)d_in[1];
  const float* bq = (const float*)d_in[2];
  const float* wk = (const float*)d_in[3];
  const float* bk = (const float*)d_in[4];
  const float* wv = (const float*)d_in[5];
  const float* bv = (const float*)d_in[6];
  const float* wo = (const float*)d_in[7];
  const float* bo = (const float*)d_in[8];

  ushort* ws  = (ushort*)d_ws;
  ushort* xb  = ws;
  ushort* wqb = ws + 4194304;
  ushort* wkb = ws + 5242880;
  ushort* wvb = ws + 6291456;
  ushort* wob = ws + 7340032;
  ushort* qbp = ws + 8388608;
  ushort* kbp = ws + 12582912;
  ushort* vtb = ws + 16777216;
  ushort* ab  = ws + 20971520;

  convert_all<<<8192, 256, 0, stream>>>(x, wq, wk, wv, wo, ws);
  gemm_qkv<<<dim3(8, 32, 3), 256, 0, stream>>>(xb, wqb, wkb, wvb, bq, bk, bv,
                                               qbp, kbp, vtb);
  attn<<<1024, 256, 0, stream>>>(qbp, kbp, vtb, ab);
  gemm_out<<<dim3(8, 32), 256, 0, stream>>>(ab, wob, bo, (float*)d_out);
}